// Round 1
// baseline (2315.108 us; speedup 1.0000x reference)
//
#include <hip/hip_runtime.h>
#include <math.h>

#define NN 1024
#define DD 256
#define CC 5
#define G3 768
#define MAXT 512
#define NA 70

__device__ __forceinline__ int scale_of(int a){ return (a<15)?0:((a<55)?1:2); }
__device__ __forceinline__ int off_of(int s){ return (s==0)?0:((s==1)?15:55); }

// K0: tpos = time_positions * audio_len ; abn = softmax(node_pred)[:,0]
__global__ void prep_kernel(const float* __restrict__ tp_in, const float* __restrict__ node_pred,
                            const float* __restrict__ audio_len,
                            float* __restrict__ tpos, float* __restrict__ abn){
  int i = blockIdx.x*blockDim.x + threadIdx.x;
  if (i >= NN) return;
  tpos[i] = tp_in[i]*audio_len[0];
  float pv[CC]; float m = -1e30f;
  for (int c=0;c<CC;++c){ pv[c]=node_pred[i*CC+c]; m=fmaxf(m,pv[c]); }
  float s=0.f;
  for (int c=0;c<CC;++c) s += expf(pv[c]-m);
  abn[i] = expf(pv[0]-m)/s;
}

// K1: per-anchor stable gather of masked node indices + counts (ballot prefix)
__global__ void order_kernel(const float* __restrict__ tpos, const float* __restrict__ anchors,
                             int* __restrict__ order, int* __restrict__ cnteff){
  int a = blockIdx.x; int lane = threadIdx.x; // 64 threads = 1 wave
  float s = anchors[2*a], e = anchors[2*a+1];
  int* ord = order + a*MAXT;
  int cnt = 0;
  for (int base=0; base<NN; base+=64){
    float tp = tpos[base+lane];
    bool msk = (tp>=s)&&(tp<=e);
    unsigned long long bal = __ballot(msk);
    int off = (int)__popcll(bal & ((1ull<<lane)-1ull));
    if (msk && (cnt+off)<MAXT) ord[cnt+off] = base+lane;
    cnt += (int)__popcll(bal);
  }
  if (lane==0){ int c = cnt<MAXT?cnt:MAXT; cnteff[2*a]=c; cnteff[2*a+1]=(c>0)?c:1; }
}

// K2: whhT[sd][k][j] = whh[sd][j][k]  (coalesced writes)
__global__ void transpose_whh(const float* __restrict__ whh, float* __restrict__ whhT){
  int idx = blockIdx.x*256 + threadIdx.x;
  if (idx >= 6*G3*DD) return;
  int sd = idx / (G3*DD);
  int r  = idx - sd*(G3*DD);
  int k  = r / G3;
  int j  = r - k*G3;
  whhT[idx] = whh[((size_t)sd*G3 + j)*DD + k];
}

// K3: E[sd][n][j] = emb[n,:] . wih[sd][j,:] + bih[sd][j]   (M=1024,N=768,K=256)x6
__global__ __launch_bounds__(256) void e_gemm(const float* __restrict__ emb, const float* __restrict__ wih,
                       const float* __restrict__ bih, float* __restrict__ E){
  int sd = blockIdx.z;
  int row0 = blockIdx.x*64, col0 = blockIdx.y*64;
  const float* W = wih + (size_t)sd*G3*DD;
  __shared__ float As[64][65];
  __shared__ float Bs[64][65];
  int tid = threadIdx.x;
  int tr = tid>>4, tc = tid&15;
  float acc[4][4] = {};
  for (int kb=0; kb<4; ++kb){
    for (int i=0;i<4;++i){
      int e4 = i*256 + tid;          // 0..1023 float4 slots of the 64x64 chunk
      int rr = e4>>4, qq = e4&15;
      float4 av = reinterpret_cast<const float4*>(emb)[ (size_t)(row0+rr)*64 + kb*16 + qq ];
      As[rr][qq*4+0]=av.x; As[rr][qq*4+1]=av.y; As[rr][qq*4+2]=av.z; As[rr][qq*4+3]=av.w;
      float4 bv = reinterpret_cast<const float4*>(W)[ (size_t)(col0+rr)*64 + kb*16 + qq ];
      Bs[rr][qq*4+0]=bv.x; Bs[rr][qq*4+1]=bv.y; Bs[rr][qq*4+2]=bv.z; Bs[rr][qq*4+3]=bv.w;
    }
    __syncthreads();
    for (int k=0;k<64;++k){
      float a0[4], b0[4];
      #pragma unroll
      for (int i=0;i<4;++i) a0[i]=As[tr*4+i][k];
      #pragma unroll
      for (int j=0;j<4;++j) b0[j]=Bs[tc*4+j][k];
      #pragma unroll
      for (int i=0;i<4;++i)
        #pragma unroll
        for (int j=0;j<4;++j)
          acc[i][j] += a0[i]*b0[j];
    }
    __syncthreads();
  }
  for (int i=0;i<4;++i){
    int row = row0 + tr*4 + i;
    for (int j=0;j<4;++j){
      int col = col0 + tc*4 + j;
      E[(size_t)sd*NN*G3 + (size_t)row*G3 + col] = acc[i][j] + bih[sd*G3+col];
    }
  }
}

// K4: per-matrix absmax -> quant scale (9 matrices: w1 x3, w2 x3, w3 x3)
__global__ void absmax_kernel(const float* __restrict__ w1, const float* __restrict__ w2,
                              const float* __restrict__ w30, const float* __restrict__ w31,
                              const float* __restrict__ w32, float* __restrict__ qs){
  int m = blockIdx.x, tid = threadIdx.x;
  const float* p; int n;
  if (m<3){ p = w1 + (size_t)m*256*519; n = 256*519; }
  else if (m<6){ p = w2 + (size_t)(m-3)*256*256; n = 256*256; }
  else { p = (m==6)?w30:((m==7)?w31:w32); n = ((m==7)?125:165)*256; }
  float mx = 0.f;
  for (int i=tid;i<n;i+=256) mx = fmaxf(mx, fabsf(p[i]));
  __shared__ float red[256];
  red[tid]=mx; __syncthreads();
  for (int sft=128; sft>0; sft>>=1){ if (tid<sft) red[tid]=fmaxf(red[tid],red[tid+sft]); __syncthreads(); }
  if (tid==0) qs[m] = fmaxf(red[0]/127.f, 1e-8f);
}

// K5: sequential GRU, one block per (anchor, direction); 768 threads = one gate output each
__global__ __launch_bounds__(768) void gru_kernel(const float* __restrict__ E, const float* __restrict__ whhT,
                           const float* __restrict__ bih, const float* __restrict__ bhh,
                           const int* __restrict__ order, const int* __restrict__ cnteff,
                           float* __restrict__ hout){
  int a = blockIdx.x>>1, d = blockIdx.x&1;
  int si = scale_of(a);
  int sd = si*2+d;
  const float* Eb = E + (size_t)sd*NN*G3;
  const float* Wt = whhT + (size_t)sd*DD*G3;
  const float* bi = bih + sd*G3;
  const float* bh = bhh + sd*G3;
  const int* ord = order + a*MAXT;
  int cnt = cnteff[2*a], eff = cnteff[2*a+1];
  __shared__ float h[DD];
  __shared__ float pre_r[DD], pre_z[DD], inn_s[DD], hn_s[DD];
  int tid = threadIdx.x;
  if (tid<DD) h[tid]=0.f;
  __syncthreads();
  for (int t=0;t<eff;++t){
    int idx = d ? (eff-1-t) : t;
    int node = (idx<cnt) ? ord[idx] : -1;
    float gi = (node>=0) ? Eb[(size_t)node*G3 + tid] : bi[tid];
    float acc = bh[tid];
    const float* w = Wt + tid;
    #pragma unroll 8
    for (int k=0;k<DD;++k) acc += h[k]*w[(size_t)k*G3];
    if (tid < DD)            pre_r[tid]      = gi+acc;
    else if (tid < 2*DD)     pre_z[tid-DD]   = gi+acc;
    else { inn_s[tid-2*DD]=gi; hn_s[tid-2*DD]=acc; }
    __syncthreads();
    if (tid < DD){
      float r = 1.f/(1.f+expf(-pre_r[tid]));
      float z = 1.f/(1.f+expf(-pre_z[tid]));
      float n = tanhf(inn_s[tid] + r*hn_s[tid]);
      h[tid] = (1.f-z)*n + z*h[tid];
    }
    __syncthreads();
  }
  if (tid<DD) hout[(size_t)(2*a+d)*DD + tid] = h[tid];
}

// K6: per-anchor MLP (int8 fake-quant on the fly) + softmax-weighted refinement head
__global__ __launch_bounds__(256) void mlp_kernel(const float* __restrict__ hout, const float* __restrict__ abn,
                           const float* __restrict__ anchors, const float* __restrict__ audio_len,
                           const float* __restrict__ w1, const float* __restrict__ w2,
                           const float* __restrict__ w30, const float* __restrict__ w31, const float* __restrict__ w32,
                           const float* __restrict__ sw0, const float* __restrict__ ew0,
                           const float* __restrict__ sw1, const float* __restrict__ ew1,
                           const float* __restrict__ sw2, const float* __restrict__ ew2,
                           const float* __restrict__ qs, float* __restrict__ out){
  int a = blockIdx.x, tid = threadIdx.x;
  int si = scale_of(a);
  int il = a - off_of(si);
  float s = anchors[2*a], e = anchors[2*a+1];
  float al = audio_len[0];
  __shared__ float feat[520];
  __shared__ float h1[256], h2[256], o[168];
  feat[tid]    = hout[(size_t)(2*a+0)*DD + tid];
  feat[DD+tid] = hout[(size_t)(2*a+1)*DD + tid];
  if (tid==0){
    feat[512]=abn[il];
    feat[513]=(s+e)*0.5f/al;
    feat[514]=(e-s)/al;
    feat[515]=0.f; feat[516]=0.f; feat[517]=0.f; feat[518]=0.f; feat[519]=0.f;
  }
  __syncthreads();
  {
    float sc = qs[si], inv = 1.f/sc;
    const float* row = w1 + ((size_t)si*256 + tid)*519;
    float acc=0.f;
    for (int k=0;k<519;++k){
      float q = rintf(row[k]*inv);
      q = fminf(fmaxf(q,-128.f),127.f);
      acc += feat[k]*(q*sc);
    }
    h1[tid]=fmaxf(acc,0.f);
  }
  __syncthreads();
  {
    float sc = qs[3+si], inv = 1.f/sc;
    const float* row = w2 + ((size_t)si*256 + tid)*256;
    float acc=0.f;
    for (int k=0;k<256;++k){
      float q = rintf(row[k]*inv);
      q = fminf(fmaxf(q,-128.f),127.f);
      acc += h1[k]*(q*sc);
    }
    h2[tid]=fmaxf(acc,0.f);
  }
  __syncthreads();
  int nout = (si==1)?125:165;
  const float* w3 = (si==0)?w30:((si==1)?w31:w32);
  if (tid<nout){
    float sc = qs[6+si], inv = 1.f/sc;
    const float* row = w3 + (size_t)tid*256;
    float acc=0.f;
    for (int k=0;k<256;++k){
      float q = rintf(row[k]*inv);
      q = fminf(fmaxf(q,-128.f),127.f);
      acc += h2[k]*(q*sc);
    }
    o[tid]=acc;
  }
  __syncthreads();
  if (tid==0){
    int b = (si==1)?60:80;
    const float* sw = (si==0)?sw0:((si==1)?sw1:sw2);
    const float* ew = (si==0)?ew0:((si==1)?ew1:ew2);
    float m=-1e30f; for (int i=0;i<b;++i) m=fmaxf(m,o[i]);
    float se=0.f, wsum=0.f;
    for (int i=0;i<b;++i){ float t=expf(o[i]-m); se+=t; wsum+=t*sw[i]; }
    float so = wsum/se;
    m=-1e30f; for (int i=0;i<b;++i) m=fmaxf(m,o[b+i]);
    se=0.f; wsum=0.f;
    for (int i=0;i<b;++i){ float t=expf(o[b+i]-m); se+=t; wsum+=t*ew[i]; }
    float eo = wsum/se;
    out[2*a]   = fminf(fmaxf(s+so,0.f),al);
    out[2*a+1] = fminf(fmaxf(e+eo,0.f),al);
    out[140+a] = o[2*b];
    for (int c2=0;c2<4;++c2) out[210+4*a+c2] = o[2*b+1+c2];
  }
}

extern "C" void kernel_launch(void* const* d_in, const int* in_sizes, int n_in,
                              void* d_out, int out_size, void* d_ws, size_t ws_size,
                              hipStream_t stream){
  const float* emb   = (const float*)d_in[0];
  const float* tpin  = (const float*)d_in[1];
  const float* npred = (const float*)d_in[2];
  const float* alen  = (const float*)d_in[3];
  const float* anch  = (const float*)d_in[4];
  const float* wih   = (const float*)d_in[5];
  const float* whh   = (const float*)d_in[6];
  const float* bih   = (const float*)d_in[7];
  const float* bhh   = (const float*)d_in[8];
  const float* w1    = (const float*)d_in[9];
  const float* w2    = (const float*)d_in[10];
  const float* w30   = (const float*)d_in[11];
  const float* w31   = (const float*)d_in[12];
  const float* w32   = (const float*)d_in[13];
  const float* sw0   = (const float*)d_in[14];
  const float* ew0   = (const float*)d_in[15];
  const float* sw1   = (const float*)d_in[16];
  const float* ew1   = (const float*)d_in[17];
  const float* sw2   = (const float*)d_in[18];
  const float* ew2   = (const float*)d_in[19];

  char* ws = (char*)d_ws;
  size_t off = 0;
  auto take = [&](size_t bytes)->char*{
    char* p = ws + off;
    off = (off + bytes + 255) & ~(size_t)255;
    return p;
  };
  float* tpos   = (float*)take((size_t)NN*4);
  float* abn    = (float*)take((size_t)NN*4);
  int*   order_ = (int*)  take((size_t)NA*MAXT*4);
  int*   cnteff = (int*)  take((size_t)NA*2*4);
  float* qs     = (float*)take(16*4);
  float* whhT   = (float*)take((size_t)6*DD*G3*4);
  float* E      = (float*)take((size_t)6*NN*G3*4);
  float* hout   = (float*)take((size_t)NA*2*DD*4);
  (void)ws_size; (void)in_sizes; (void)n_in; (void)out_size;

  prep_kernel<<<dim3((NN+255)/256), dim3(256), 0, stream>>>(tpin, npred, alen, tpos, abn);
  order_kernel<<<dim3(NA), dim3(64), 0, stream>>>(tpos, anch, order_, cnteff);
  transpose_whh<<<dim3((6*G3*DD+255)/256), dim3(256), 0, stream>>>(whh, whhT);
  e_gemm<<<dim3(16,12,6), dim3(256), 0, stream>>>(emb, wih, bih, E);
  absmax_kernel<<<dim3(9), dim3(256), 0, stream>>>(w1, w2, w30, w31, w32, qs);
  gru_kernel<<<dim3(NA*2), dim3(768), 0, stream>>>(E, whhT, bih, bhh, order_, cnteff, hout);
  mlp_kernel<<<dim3(NA), dim3(256), 0, stream>>>(hout, abn, anch, alen, w1, w2, w30, w31, w32,
                                                 sw0, ew0, sw1, ew1, sw2, ew2, qs, (float*)d_out);
}

// Round 2
// 685.806 us; speedup vs baseline: 3.3757x; 3.3757x over previous
//
#include <hip/hip_runtime.h>
#include <math.h>

#define NN 1024
#define DD 256
#define CC 5
#define G3 768
#define MAXT 512
#define NA 70

typedef _Float16 h2v __attribute__((ext_vector_type(2)));

__device__ __forceinline__ int scale_of(int a){ return (a<15)?0:((a<55)?1:2); }
__device__ __forceinline__ int off_of(int s){ return (s==0)?0:((s==1)?15:55); }

__device__ __forceinline__ h2v bc_h2(unsigned int u){ return __builtin_bit_cast(h2v, u); }

#if defined(__has_builtin)
#if __has_builtin(__builtin_amdgcn_fdot2)
#define HAVE_FDOT2 1
#endif
#endif

__device__ __forceinline__ float fdot2f(unsigned int w, unsigned int h, float c){
  h2v wv = bc_h2(w), hv = bc_h2(h);
#ifdef HAVE_FDOT2
  return __builtin_amdgcn_fdot2(wv, hv, c, false);
#else
  return c + (float)wv.x*(float)hv.x + (float)wv.y*(float)hv.y;
#endif
}

// K0: tpos = time_positions * audio_len ; abn = softmax(node_pred)[:,0]
__global__ void prep_kernel(const float* __restrict__ tp_in, const float* __restrict__ node_pred,
                            const float* __restrict__ audio_len,
                            float* __restrict__ tpos, float* __restrict__ abn){
  int i = blockIdx.x*blockDim.x + threadIdx.x;
  if (i >= NN) return;
  tpos[i] = tp_in[i]*audio_len[0];
  float pv[CC]; float m = -1e30f;
  for (int c=0;c<CC;++c){ pv[c]=node_pred[i*CC+c]; m=fmaxf(m,pv[c]); }
  float s=0.f;
  for (int c=0;c<CC;++c) s += expf(pv[c]-m);
  abn[i] = expf(pv[0]-m)/s;
}

// K1: per-anchor stable gather of masked node indices + counts (ballot prefix)
__global__ void order_kernel(const float* __restrict__ tpos, const float* __restrict__ anchors,
                             int* __restrict__ order, int* __restrict__ cnteff){
  int a = blockIdx.x; int lane = threadIdx.x; // 64 threads = 1 wave
  float s = anchors[2*a], e = anchors[2*a+1];
  int* ord = order + a*MAXT;
  int cnt = 0;
  for (int base=0; base<NN; base+=64){
    float tp = tpos[base+lane];
    bool msk = (tp>=s)&&(tp<=e);
    unsigned long long bal = __ballot(msk);
    int off = (int)__popcll(bal & ((1ull<<lane)-1ull));
    if (msk && (cnt+off)<MAXT) ord[cnt+off] = base+lane;
    cnt += (int)__popcll(bal);
  }
  if (lane==0){ int c = cnt<MAXT?cnt:MAXT; cnteff[2*a]=c; cnteff[2*a+1]=(c>0)?c:1; }
}

// K2: pack whh -> fp16 pairs along k:  whhP[(sd*768+j)*128 + k2] = (h16(w[j][2k2]), h16(w[j][2k2+1]))
__global__ void pack_whh(const float* __restrict__ whh, unsigned int* __restrict__ whhP){
  int idx = blockIdx.x*256 + threadIdx.x;
  if (idx >= 6*G3*128) return;
  int k2 = idx & 127;
  int jsd = idx >> 7;              // sd*768 + j
  const float* src = whh + (size_t)jsd*DD + 2*k2;
  _Float16 a = (_Float16)src[0];
  _Float16 b = (_Float16)src[1];
  unsigned short ua = __builtin_bit_cast(unsigned short, a);
  unsigned short ub = __builtin_bit_cast(unsigned short, b);
  whhP[idx] = (unsigned int)ua | ((unsigned int)ub << 16);
}

// K3: E[sd][n][j] = emb[n,:] . wih[sd][j,:] + bih[sd][j]   (M=1024,N=768,K=256)x6
__global__ __launch_bounds__(256) void e_gemm(const float* __restrict__ emb, const float* __restrict__ wih,
                       const float* __restrict__ bih, float* __restrict__ E){
  int sd = blockIdx.z;
  int row0 = blockIdx.x*64, col0 = blockIdx.y*64;
  const float* W = wih + (size_t)sd*G3*DD;
  __shared__ float As[64][65];
  __shared__ float Bs[64][65];
  int tid = threadIdx.x;
  int tr = tid>>4, tc = tid&15;
  float acc[4][4] = {};
  for (int kb=0; kb<4; ++kb){
    for (int i=0;i<4;++i){
      int e4 = i*256 + tid;
      int rr = e4>>4, qq = e4&15;
      float4 av = reinterpret_cast<const float4*>(emb)[ (size_t)(row0+rr)*64 + kb*16 + qq ];
      As[rr][qq*4+0]=av.x; As[rr][qq*4+1]=av.y; As[rr][qq*4+2]=av.z; As[rr][qq*4+3]=av.w;
      float4 bv = reinterpret_cast<const float4*>(W)[ (size_t)(col0+rr)*64 + kb*16 + qq ];
      Bs[rr][qq*4+0]=bv.x; Bs[rr][qq*4+1]=bv.y; Bs[rr][qq*4+2]=bv.z; Bs[rr][qq*4+3]=bv.w;
    }
    __syncthreads();
    for (int k=0;k<64;++k){
      float a0[4], b0[4];
      #pragma unroll
      for (int i=0;i<4;++i) a0[i]=As[tr*4+i][k];
      #pragma unroll
      for (int j=0;j<4;++j) b0[j]=Bs[tc*4+j][k];
      #pragma unroll
      for (int i=0;i<4;++i)
        #pragma unroll
        for (int j=0;j<4;++j)
          acc[i][j] += a0[i]*b0[j];
    }
    __syncthreads();
  }
  for (int i=0;i<4;++i){
    int row = row0 + tr*4 + i;
    for (int j=0;j<4;++j){
      int col = col0 + tc*4 + j;
      E[(size_t)sd*NN*G3 + (size_t)row*G3 + col] = acc[i][j] + bih[sd*G3+col];
    }
  }
}

// K4: per-matrix absmax -> quant scale (9 matrices)
__global__ void absmax_kernel(const float* __restrict__ w1, const float* __restrict__ w2,
                              const float* __restrict__ w30, const float* __restrict__ w31,
                              const float* __restrict__ w32, float* __restrict__ qs){
  int m = blockIdx.x, tid = threadIdx.x;
  const float* p; int n;
  if (m<3){ p = w1 + (size_t)m*256*519; n = 256*519; }
  else if (m<6){ p = w2 + (size_t)(m-3)*256*256; n = 256*256; }
  else { p = (m==6)?w30:((m==7)?w31:w32); n = ((m==7)?125:165)*256; }
  float mx = 0.f;
  for (int i=tid;i<n;i+=256) mx = fmaxf(mx, fabsf(p[i]));
  __shared__ float red[256];
  red[tid]=mx; __syncthreads();
  for (int sft=128; sft>0; sft>>=1){ if (tid<sft) red[tid]=fmaxf(red[tid],red[tid+sft]); __syncthreads(); }
  if (tid==0) qs[m] = fmaxf(red[0]/127.f, 1e-8f);
}

// K5: sequential GRU, one block per (anchor, direction); 768 threads = one gate column each.
// whh (fp16, packed pairs) lives permanently in each thread's VGPRs: 128 regs.
__global__ __launch_bounds__(768, 3) void gru_kernel(
                           const float* __restrict__ E, const unsigned int* __restrict__ whhP,
                           const float* __restrict__ bih, const float* __restrict__ bhh,
                           const int* __restrict__ order, const int* __restrict__ cnteff,
                           float* __restrict__ hout){
  int a = blockIdx.x>>1, d = blockIdx.x&1;
  int si = scale_of(a);
  int sd = si*2+d;
  int tid = threadIdx.x;
  const float* Ebt = E + (size_t)sd*NN*G3 + tid;
  const float* bi = bih + sd*G3;
  const float* bh = bhh + sd*G3;
  const int* ord = order + a*MAXT;

  __shared__ int ord_s[MAXT];
  __shared__ alignas(16) _Float16 h16h[DD];     // fp16 copy of h for the dot
  __shared__ float h32[DD];                      // f32 master copy of h
  __shared__ float pre_r[DD], pre_z[DD], inn_s[DD], hn_s[DD];

  // preload order list + init h
  if (tid < MAXT) ord_s[tid] = ord[tid];
  if (tid < DD){ h32[tid] = 0.f; h16h[tid] = (_Float16)0.f; }

  int cnt = cnteff[2*a], eff = cnteff[2*a+1];
  float bh_r = bh[tid];
  float bi_r = bi[tid];

  // load this thread's weight column (256 fp16 = 128 packed dwords) into registers
  unsigned int wreg[128];
  {
    const uint4* wp = (const uint4*)(whhP + ((size_t)sd*G3 + tid)*128);
    #pragma unroll
    for (int i=0;i<32;++i){
      uint4 v = wp[i];
      wreg[4*i+0]=v.x; wreg[4*i+1]=v.y; wreg[4*i+2]=v.z; wreg[4*i+3]=v.w;
    }
  }
  __syncthreads();

  // software prefetch of the first E row
  float gi_next;
  {
    int idx0 = d ? (eff-1) : 0;
    int n0 = (idx0 < cnt) ? ord_s[idx0] : -1;
    gi_next = (n0>=0) ? Ebt[(size_t)n0*G3] : bi_r;
  }

  const uint4* hp = (const uint4*)h16h;   // 32 x (8 fp16) uniform broadcast reads

  for (int t=0;t<eff;++t){
    float gi = gi_next;
    if (t+1 < eff){
      int idx1 = d ? (eff-2-t) : (t+1);
      int n1 = (idx1 < cnt) ? ord_s[idx1] : -1;
      gi_next = (n1>=0) ? Ebt[(size_t)n1*G3] : bi_r;
    }

    float acc = bh_r;
    #pragma unroll
    for (int kk=0;kk<32;++kk){
      uint4 hv = hp[kk];
      acc = fdot2f(wreg[4*kk+0], hv.x, acc);
      acc = fdot2f(wreg[4*kk+1], hv.y, acc);
      acc = fdot2f(wreg[4*kk+2], hv.z, acc);
      acc = fdot2f(wreg[4*kk+3], hv.w, acc);
    }

    if (tid < DD)            pre_r[tid]      = gi+acc;
    else if (tid < 2*DD)     pre_z[tid-DD]   = gi+acc;
    else { inn_s[tid-2*DD]=gi; hn_s[tid-2*DD]=acc; }
    __syncthreads();
    if (tid < DD){
      float r = 1.f/(1.f+expf(-pre_r[tid]));
      float z = 1.f/(1.f+expf(-pre_z[tid]));
      float n = tanhf(inn_s[tid] + r*hn_s[tid]);
      float hnew = (1.f-z)*n + z*h32[tid];
      h32[tid] = hnew;
      h16h[tid] = (_Float16)hnew;
    }
    __syncthreads();
  }
  if (tid<DD) hout[(size_t)(2*a+d)*DD + tid] = h32[tid];
}

// K6: per-anchor MLP (int8 fake-quant on the fly) + softmax-weighted refinement head
__global__ __launch_bounds__(256) void mlp_kernel(const float* __restrict__ hout, const float* __restrict__ abn,
                           const float* __restrict__ anchors, const float* __restrict__ audio_len,
                           const float* __restrict__ w1, const float* __restrict__ w2,
                           const float* __restrict__ w30, const float* __restrict__ w31, const float* __restrict__ w32,
                           const float* __restrict__ sw0, const float* __restrict__ ew0,
                           const float* __restrict__ sw1, const float* __restrict__ ew1,
                           const float* __restrict__ sw2, const float* __restrict__ ew2,
                           const float* __restrict__ qs, float* __restrict__ out){
  int a = blockIdx.x, tid = threadIdx.x;
  int si = scale_of(a);
  int il = a - off_of(si);
  float s = anchors[2*a], e = anchors[2*a+1];
  float al = audio_len[0];
  __shared__ float feat[520];
  __shared__ float h1[256], h2[256], o[168];
  feat[tid]    = hout[(size_t)(2*a+0)*DD + tid];
  feat[DD+tid] = hout[(size_t)(2*a+1)*DD + tid];
  if (tid==0){
    feat[512]=abn[il];
    feat[513]=(s+e)*0.5f/al;
    feat[514]=(e-s)/al;
    feat[515]=0.f; feat[516]=0.f; feat[517]=0.f; feat[518]=0.f; feat[519]=0.f;
  }
  __syncthreads();
  {
    float sc = qs[si], inv = 1.f/sc;
    const float* row = w1 + ((size_t)si*256 + tid)*519;
    float acc=0.f;
    for (int k=0;k<519;++k){
      float q = rintf(row[k]*inv);
      q = fminf(fmaxf(q,-128.f),127.f);
      acc += feat[k]*(q*sc);
    }
    h1[tid]=fmaxf(acc,0.f);
  }
  __syncthreads();
  {
    float sc = qs[3+si], inv = 1.f/sc;
    const float* row = w2 + ((size_t)si*256 + tid)*256;
    float acc=0.f;
    for (int k=0;k<256;++k){
      float q = rintf(row[k]*inv);
      q = fminf(fmaxf(q,-128.f),127.f);
      acc += h1[k]*(q*sc);
    }
    h2[tid]=fmaxf(acc,0.f);
  }
  __syncthreads();
  int nout = (si==1)?125:165;
  const float* w3 = (si==0)?w30:((si==1)?w31:w32);
  if (tid<nout){
    float sc = qs[6+si], inv = 1.f/sc;
    const float* row = w3 + (size_t)tid*256;
    float acc=0.f;
    for (int k=0;k<256;++k){
      float q = rintf(row[k]*inv);
      q = fminf(fmaxf(q,-128.f),127.f);
      acc += h2[k]*(q*sc);
    }
    o[tid]=acc;
  }
  __syncthreads();
  if (tid==0){
    int b = (si==1)?60:80;
    const float* sw = (si==0)?sw0:((si==1)?sw1:sw2);
    const float* ew = (si==0)?ew0:((si==1)?ew1:ew2);
    float m=-1e30f; for (int i=0;i<b;++i) m=fmaxf(m,o[i]);
    float se=0.f, wsum=0.f;
    for (int i=0;i<b;++i){ float t=expf(o[i]-m); se+=t; wsum+=t*sw[i]; }
    float so = wsum/se;
    m=-1e30f; for (int i=0;i<b;++i) m=fmaxf(m,o[b+i]);
    se=0.f; wsum=0.f;
    for (int i=0;i<b;++i){ float t=expf(o[b+i]-m); se+=t; wsum+=t*ew[i]; }
    float eo = wsum/se;
    out[2*a]   = fminf(fmaxf(s+so,0.f),al);
    out[2*a+1] = fminf(fmaxf(e+eo,0.f),al);
    out[140+a] = o[2*b];
    for (int c2=0;c2<4;++c2) out[210+4*a+c2] = o[2*b+1+c2];
  }
}

extern "C" void kernel_launch(void* const* d_in, const int* in_sizes, int n_in,
                              void* d_out, int out_size, void* d_ws, size_t ws_size,
                              hipStream_t stream){
  const float* emb   = (const float*)d_in[0];
  const float* tpin  = (const float*)d_in[1];
  const float* npred = (const float*)d_in[2];
  const float* alen  = (const float*)d_in[3];
  const float* anch  = (const float*)d_in[4];
  const float* wih   = (const float*)d_in[5];
  const float* whh   = (const float*)d_in[6];
  const float* bih   = (const float*)d_in[7];
  const float* bhh   = (const float*)d_in[8];
  const float* w1    = (const float*)d_in[9];
  const float* w2    = (const float*)d_in[10];
  const float* w30   = (const float*)d_in[11];
  const float* w31   = (const float*)d_in[12];
  const float* w32   = (const float*)d_in[13];
  const float* sw0   = (const float*)d_in[14];
  const float* ew0   = (const float*)d_in[15];
  const float* sw1   = (const float*)d_in[16];
  const float* ew1   = (const float*)d_in[17];
  const float* sw2   = (const float*)d_in[18];
  const float* ew2   = (const float*)d_in[19];

  char* ws = (char*)d_ws;
  size_t off = 0;
  auto take = [&](size_t bytes)->char*{
    char* p = ws + off;
    off = (off + bytes + 255) & ~(size_t)255;
    return p;
  };
  float* tpos   = (float*)take((size_t)NN*4);
  float* abn    = (float*)take((size_t)NN*4);
  int*   order_ = (int*)  take((size_t)NA*MAXT*4);
  int*   cnteff = (int*)  take((size_t)NA*2*4);
  float* qs     = (float*)take(16*4);
  unsigned int* whhP = (unsigned int*)take((size_t)6*G3*128*4);
  float* E      = (float*)take((size_t)6*NN*G3*4);
  float* hout   = (float*)take((size_t)NA*2*DD*4);
  (void)ws_size; (void)in_sizes; (void)n_in; (void)out_size;

  prep_kernel<<<dim3((NN+255)/256), dim3(256), 0, stream>>>(tpin, npred, alen, tpos, abn);
  order_kernel<<<dim3(NA), dim3(64), 0, stream>>>(tpos, anch, order_, cnteff);
  pack_whh<<<dim3((6*G3*128+255)/256), dim3(256), 0, stream>>>(whh, whhP);
  e_gemm<<<dim3(16,12,6), dim3(256), 0, stream>>>(emb, wih, bih, E);
  absmax_kernel<<<dim3(9), dim3(256), 0, stream>>>(w1, w2, w30, w31, w32, qs);
  gru_kernel<<<dim3(NA*2), dim3(768), 0, stream>>>(E, whhP, bih, bhh, order_, cnteff, hout);
  mlp_kernel<<<dim3(NA), dim3(256), 0, stream>>>(hout, abn, anch, alen, w1, w2, w30, w31, w32,
                                                 sw0, ew0, sw1, ew1, sw2, ew2, qs, (float*)d_out);
}

// Round 3
// 672.393 us; speedup vs baseline: 3.4431x; 1.0199x over previous
//
#include <hip/hip_runtime.h>
#include <math.h>

#define NN 1024
#define DD 256
#define CC 5
#define G3 768
#define MAXT 512
#define NA 70

typedef _Float16 v8h __attribute__((ext_vector_type(8)));
typedef float v4f __attribute__((ext_vector_type(4)));

__device__ __forceinline__ int scale_of(int a){ return (a<15)?0:((a<55)?1:2); }
__device__ __forceinline__ int off_of(int s){ return (s==0)?0:((s==1)?15:55); }

// K0: tpos = time_positions * audio_len ; abn = softmax(node_pred)[:,0]
__global__ void prep_kernel(const float* __restrict__ tp_in, const float* __restrict__ node_pred,
                            const float* __restrict__ audio_len,
                            float* __restrict__ tpos, float* __restrict__ abn){
  int i = blockIdx.x*blockDim.x + threadIdx.x;
  if (i >= NN) return;
  tpos[i] = tp_in[i]*audio_len[0];
  float pv[CC]; float m = -1e30f;
  for (int c=0;c<CC;++c){ pv[c]=node_pred[i*CC+c]; m=fmaxf(m,pv[c]); }
  float s=0.f;
  for (int c=0;c<CC;++c) s += expf(pv[c]-m);
  abn[i] = expf(pv[0]-m)/s;
}

// K1: per-anchor stable gather of masked node indices + counts (ballot prefix)
__global__ void order_kernel(const float* __restrict__ tpos, const float* __restrict__ anchors,
                             int* __restrict__ order, int* __restrict__ cnteff){
  int a = blockIdx.x; int lane = threadIdx.x; // 64 threads = 1 wave
  float s = anchors[2*a], e = anchors[2*a+1];
  int* ord = order + a*MAXT;
  int cnt = 0;
  for (int base=0; base<NN; base+=64){
    float tp = tpos[base+lane];
    bool msk = (tp>=s)&&(tp<=e);
    unsigned long long bal = __ballot(msk);
    int off = (int)__popcll(bal & ((1ull<<lane)-1ull));
    if (msk && (cnt+off)<MAXT) ord[cnt+off] = base+lane;
    cnt += (int)__popcll(bal);
  }
  if (lane==0){ int c = cnt<MAXT?cnt:MAXT; cnteff[2*a]=c; cnteff[2*a+1]=(c>0)?c:1; }
}

// K2: pack whh into MFMA B-fragment order (fp16 pairs).
// Layout: idx = ((((sd*12 + w)*64 + lane)*8 + q)*4 + nt)*4 + r
//   gate j = w*64 + nt*16 + (lane&15) ;  k = 32*q + 8*(lane>>4) + 2*r (+1)
__global__ void pack_whhB(const float* __restrict__ whh, unsigned int* __restrict__ dst){
  int idx = blockIdx.x*256 + threadIdx.x;
  if (idx >= 6*12*64*128) return;
  int r    = idx & 3;
  int nt   = (idx>>2) & 3;
  int q    = (idx>>4) & 7;
  int lane = (idx>>7) & 63;
  int sw   = idx >> 13;          // sd*12 + w
  int w    = sw % 12;
  int sd   = sw / 12;
  int j = w*64 + nt*16 + (lane&15);
  int k = 32*q + 8*(lane>>4) + 2*r;
  const float* src = whh + ((size_t)sd*G3 + j)*DD + k;
  _Float16 a = (_Float16)src[0];
  _Float16 b = (_Float16)src[1];
  unsigned short ua = __builtin_bit_cast(unsigned short, a);
  unsigned short ub = __builtin_bit_cast(unsigned short, b);
  dst[idx] = (unsigned int)ua | ((unsigned int)ub << 16);
}

// K3: E[sd][n][j] = emb[n,:] . wih[sd][j,:] + bih[sd][j]   (M=1024,N=768,K=256)x6
__global__ __launch_bounds__(256) void e_gemm(const float* __restrict__ emb, const float* __restrict__ wih,
                       const float* __restrict__ bih, float* __restrict__ E){
  int sd = blockIdx.z;
  int row0 = blockIdx.x*64, col0 = blockIdx.y*64;
  const float* W = wih + (size_t)sd*G3*DD;
  __shared__ float As[64][65];
  __shared__ float Bs[64][65];
  int tid = threadIdx.x;
  int tr = tid>>4, tc = tid&15;
  float acc[4][4] = {};
  for (int kb=0; kb<4; ++kb){
    for (int i=0;i<4;++i){
      int e4 = i*256 + tid;
      int rr = e4>>4, qq = e4&15;
      float4 av = reinterpret_cast<const float4*>(emb)[ (size_t)(row0+rr)*64 + kb*16 + qq ];
      As[rr][qq*4+0]=av.x; As[rr][qq*4+1]=av.y; As[rr][qq*4+2]=av.z; As[rr][qq*4+3]=av.w;
      float4 bv = reinterpret_cast<const float4*>(W)[ (size_t)(col0+rr)*64 + kb*16 + qq ];
      Bs[rr][qq*4+0]=bv.x; Bs[rr][qq*4+1]=bv.y; Bs[rr][qq*4+2]=bv.z; Bs[rr][qq*4+3]=bv.w;
    }
    __syncthreads();
    for (int k=0;k<64;++k){
      float a0[4], b0[4];
      #pragma unroll
      for (int i=0;i<4;++i) a0[i]=As[tr*4+i][k];
      #pragma unroll
      for (int j=0;j<4;++j) b0[j]=Bs[tc*4+j][k];
      #pragma unroll
      for (int i=0;i<4;++i)
        #pragma unroll
        for (int j=0;j<4;++j)
          acc[i][j] += a0[i]*b0[j];
    }
    __syncthreads();
  }
  for (int i=0;i<4;++i){
    int row = row0 + tr*4 + i;
    for (int j=0;j<4;++j){
      int col = col0 + tc*4 + j;
      E[(size_t)sd*NN*G3 + (size_t)row*G3 + col] = acc[i][j] + bih[sd*G3+col];
    }
  }
}

// K4: per-matrix absmax -> quant scale (9 matrices)
__global__ void absmax_kernel(const float* __restrict__ w1, const float* __restrict__ w2,
                              const float* __restrict__ w30, const float* __restrict__ w31,
                              const float* __restrict__ w32, float* __restrict__ qs){
  int m = blockIdx.x, tid = threadIdx.x;
  const float* p; int n;
  if (m<3){ p = w1 + (size_t)m*256*519; n = 256*519; }
  else if (m<6){ p = w2 + (size_t)(m-3)*256*256; n = 256*256; }
  else { p = (m==6)?w30:((m==7)?w31:w32); n = ((m==7)?125:165)*256; }
  float mx = 0.f;
  for (int i=tid;i<n;i+=256) mx = fmaxf(mx, fabsf(p[i]));
  __shared__ float red[256];
  red[tid]=mx; __syncthreads();
  for (int sft=128; sft>0; sft>>=1){ if (tid<sft) red[tid]=fmaxf(red[tid],red[tid+sft]); __syncthreads(); }
  if (tid==0) qs[m] = fmaxf(red[0]/127.f, 1e-8f);
}

// K5: sequential GRU via per-wave MFMA. One block per (anchor, direction).
// 768 threads = 12 waves; wave w owns gates [w*64, w*64+64) as 4 n-tiles of 16.
// Weights resident as MFMA B-fragments (128 dwords/thread, MFMA reads VGPR/AGPR directly).
__global__ __launch_bounds__(768, 3) void gru_kernel(
                           const float* __restrict__ E, const unsigned int* __restrict__ whhB,
                           const float* __restrict__ bih, const float* __restrict__ bhh,
                           const int* __restrict__ order, const int* __restrict__ cnteff,
                           float* __restrict__ hout){
  int a = blockIdx.x>>1, d = blockIdx.x&1;
  int si = scale_of(a);
  int sd = si*2+d;
  int tid = threadIdx.x;
  int w = tid>>6, lane = tid&63;
  int g16 = lane>>4;
  const float* Ebt = E + (size_t)sd*NN*G3 + tid;   // gi for gate j = tid
  const int* ord = order + a*MAXT;

  __shared__ int ord_s[MAXT];
  __shared__ alignas(16) _Float16 h16h[DD];
  __shared__ float h32[DD];
  __shared__ float pre_r[DD], pre_z[DD], inn_s[DD], hn_s[DD];

  if (tid < MAXT) ord_s[tid] = ord[tid];
  if (tid < DD){ h32[tid] = 0.f; h16h[tid] = (_Float16)0.f; }

  int cnt = cnteff[2*a], eff = cnteff[2*a+1];
  float bh_r = bhh[sd*G3 + tid];
  float bi_r = bih[sd*G3 + tid];

  // load this thread's B fragments: 32 x uint4 = 128 dwords, contiguous per thread
  v8h bfrag[8][4];
  {
    const uint4* wp = reinterpret_cast<const uint4*>(whhB) + (((size_t)sd*12 + w)*64 + lane)*32;
    #pragma unroll
    for (int q=0;q<8;++q)
      #pragma unroll
      for (int nt=0;nt<4;++nt)
        bfrag[q][nt] = __builtin_bit_cast(v8h, wp[q*4+nt]);
  }
  __syncthreads();

  // software prefetch of the first E row
  float gi_next;
  {
    int idx0 = d ? (eff-1) : 0;
    int n0 = (idx0 < cnt) ? ord_s[idx0] : -1;
    gi_next = (n0>=0) ? Ebt[(size_t)n0*G3] : bi_r;
  }

  const _Float16* hb = h16h + g16*8;   // this lane-group's A chunk base

  for (int t=0;t<eff;++t){
    float gi = gi_next;
    if (t+1 < eff){
      int idx1 = d ? (eff-2-t) : (t+1);
      int n1 = (idx1 < cnt) ? ord_s[idx1] : -1;
      gi_next = (n1>=0) ? Ebt[(size_t)n1*G3] : bi_r;
    }

    v4f acc0 = {0.f,0.f,0.f,0.f}, acc1 = {0.f,0.f,0.f,0.f};
    v4f acc2 = {0.f,0.f,0.f,0.f}, acc3 = {0.f,0.f,0.f,0.f};
    #pragma unroll
    for (int q=0;q<8;++q){
      v8h af = *reinterpret_cast<const v8h*>(hb + 32*q);
      acc0 = __builtin_amdgcn_mfma_f32_16x16x32_f16(af, bfrag[q][0], acc0, 0,0,0);
      acc1 = __builtin_amdgcn_mfma_f32_16x16x32_f16(af, bfrag[q][1], acc1, 0,0,0);
      acc2 = __builtin_amdgcn_mfma_f32_16x16x32_f16(af, bfrag[q][2], acc2, 0,0,0);
      acc3 = __builtin_amdgcn_mfma_f32_16x16x32_f16(af, bfrag[q][3], acc3, 0,0,0);
    }
    float v0 = acc0[0], v1 = acc1[0], v2 = acc2[0], v3 = acc3[0];
    float va = (g16==0)?v0:((g16==1)?v1:((g16==2)?v2:v3));
    float val = va + bh_r;               // Whh.h + bhh  for gate j = tid

    if (tid < DD)            pre_r[tid]      = gi + val;
    else if (tid < 2*DD)     pre_z[tid-DD]   = gi + val;
    else { inn_s[tid-2*DD] = gi; hn_s[tid-2*DD] = val; }
    __syncthreads();
    if (tid < DD){
      float r = 1.f/(1.f+expf(-pre_r[tid]));
      float z = 1.f/(1.f+expf(-pre_z[tid]));
      float n = tanhf(inn_s[tid] + r*hn_s[tid]);
      float hnew = (1.f-z)*n + z*h32[tid];
      h32[tid] = hnew;
      h16h[tid] = (_Float16)hnew;
    }
    __syncthreads();
  }
  if (tid<DD) hout[(size_t)(2*a+d)*DD + tid] = h32[tid];
}

// K6: per-anchor MLP (int8 fake-quant on the fly) + softmax-weighted refinement head
__global__ __launch_bounds__(256) void mlp_kernel(const float* __restrict__ hout, const float* __restrict__ abn,
                           const float* __restrict__ anchors, const float* __restrict__ audio_len,
                           const float* __restrict__ w1, const float* __restrict__ w2,
                           const float* __restrict__ w30, const float* __restrict__ w31, const float* __restrict__ w32,
                           const float* __restrict__ sw0, const float* __restrict__ ew0,
                           const float* __restrict__ sw1, const float* __restrict__ ew1,
                           const float* __restrict__ sw2, const float* __restrict__ ew2,
                           const float* __restrict__ qs, float* __restrict__ out){
  int a = blockIdx.x, tid = threadIdx.x;
  int si = scale_of(a);
  int il = a - off_of(si);
  float s = anchors[2*a], e = anchors[2*a+1];
  float al = audio_len[0];
  __shared__ float feat[520];
  __shared__ float h1[256], h2[256], o[168];
  feat[tid]    = hout[(size_t)(2*a+0)*DD + tid];
  feat[DD+tid] = hout[(size_t)(2*a+1)*DD + tid];
  if (tid==0){
    feat[512]=abn[il];
    feat[513]=(s+e)*0.5f/al;
    feat[514]=(e-s)/al;
    feat[515]=0.f; feat[516]=0.f; feat[517]=0.f; feat[518]=0.f; feat[519]=0.f;
  }
  __syncthreads();
  {
    float sc = qs[si], inv = 1.f/sc;
    const float* row = w1 + ((size_t)si*256 + tid)*519;
    float acc=0.f;
    for (int k=0;k<519;++k){
      float q = rintf(row[k]*inv);
      q = fminf(fmaxf(q,-128.f),127.f);
      acc += feat[k]*(q*sc);
    }
    h1[tid]=fmaxf(acc,0.f);
  }
  __syncthreads();
  {
    float sc = qs[3+si], inv = 1.f/sc;
    const float* row = w2 + ((size_t)si*256 + tid)*256;
    float acc=0.f;
    for (int k=0;k<256;++k){
      float q = rintf(row[k]*inv);
      q = fminf(fmaxf(q,-128.f),127.f);
      acc += h1[k]*(q*sc);
    }
    h2[tid]=fmaxf(acc,0.f);
  }
  __syncthreads();
  int nout = (si==1)?125:165;
  const float* w3 = (si==0)?w30:((si==1)?w31:w32);
  if (tid<nout){
    float sc = qs[6+si], inv = 1.f/sc;
    const float* row = w3 + (size_t)tid*256;
    float acc=0.f;
    for (int k=0;k<256;++k){
      float q = rintf(row[k]*inv);
      q = fminf(fmaxf(q,-128.f),127.f);
      acc += h2[k]*(q*sc);
    }
    o[tid]=acc;
  }
  __syncthreads();
  if (tid==0){
    int b = (si==1)?60:80;
    const float* sw = (si==0)?sw0:((si==1)?sw1:sw2);
    const float* ew = (si==0)?ew0:((si==1)?ew1:ew2);
    float m=-1e30f; for (int i=0;i<b;++i) m=fmaxf(m,o[i]);
    float se=0.f, wsum=0.f;
    for (int i=0;i<b;++i){ float t=expf(o[i]-m); se+=t; wsum+=t*sw[i]; }
    float so = wsum/se;
    m=-1e30f; for (int i=0;i<b;++i) m=fmaxf(m,o[b+i]);
    se=0.f; wsum=0.f;
    for (int i=0;i<b;++i){ float t=expf(o[b+i]-m); se+=t; wsum+=t*ew[i]; }
    float eo = wsum/se;
    out[2*a]   = fminf(fmaxf(s+so,0.f),al);
    out[2*a+1] = fminf(fmaxf(e+eo,0.f),al);
    out[140+a] = o[2*b];
    for (int c2=0;c2<4;++c2) out[210+4*a+c2] = o[2*b+1+c2];
  }
}

extern "C" void kernel_launch(void* const* d_in, const int* in_sizes, int n_in,
                              void* d_out, int out_size, void* d_ws, size_t ws_size,
                              hipStream_t stream){
  const float* emb   = (const float*)d_in[0];
  const float* tpin  = (const float*)d_in[1];
  const float* npred = (const float*)d_in[2];
  const float* alen  = (const float*)d_in[3];
  const float* anch  = (const float*)d_in[4];
  const float* wih   = (const float*)d_in[5];
  const float* whh   = (const float*)d_in[6];
  const float* bih   = (const float*)d_in[7];
  const float* bhh   = (const float*)d_in[8];
  const float* w1    = (const float*)d_in[9];
  const float* w2    = (const float*)d_in[10];
  const float* w30   = (const float*)d_in[11];
  const float* w31   = (const float*)d_in[12];
  const float* w32   = (const float*)d_in[13];
  const float* sw0   = (const float*)d_in[14];
  const float* ew0   = (const float*)d_in[15];
  const float* sw1   = (const float*)d_in[16];
  const float* ew1   = (const float*)d_in[17];
  const float* sw2   = (const float*)d_in[18];
  const float* ew2   = (const float*)d_in[19];

  char* ws = (char*)d_ws;
  size_t off = 0;
  auto take = [&](size_t bytes)->char*{
    char* p = ws + off;
    off = (off + bytes + 255) & ~(size_t)255;
    return p;
  };
  float* tpos   = (float*)take((size_t)NN*4);
  float* abn    = (float*)take((size_t)NN*4);
  int*   order_ = (int*)  take((size_t)NA*MAXT*4);
  int*   cnteff = (int*)  take((size_t)NA*2*4);
  float* qs     = (float*)take(16*4);
  unsigned int* whhB = (unsigned int*)take((size_t)6*12*64*128*4);
  float* E      = (float*)take((size_t)6*NN*G3*4);
  float* hout   = (float*)take((size_t)NA*2*DD*4);
  (void)ws_size; (void)in_sizes; (void)n_in; (void)out_size;

  prep_kernel<<<dim3((NN+255)/256), dim3(256), 0, stream>>>(tpin, npred, alen, tpos, abn);
  order_kernel<<<dim3(NA), dim3(64), 0, stream>>>(tpos, anch, order_, cnteff);
  pack_whhB<<<dim3((6*12*64*128+255)/256), dim3(256), 0, stream>>>(whh, whhB);
  e_gemm<<<dim3(16,12,6), dim3(256), 0, stream>>>(emb, wih, bih, E);
  absmax_kernel<<<dim3(9), dim3(256), 0, stream>>>(w1, w2, w30, w31, w32, qs);
  gru_kernel<<<dim3(NA*2), dim3(768), 0, stream>>>(E, whhB, bih, bhh, order_, cnteff, hout);
  mlp_kernel<<<dim3(NA), dim3(256), 0, stream>>>(hout, abn, anch, alen, w1, w2, w30, w31, w32,
                                                 sw0, ew0, sw1, ew1, sw2, ew2, qs, (float*)d_out);
}

// Round 4
// 651.424 us; speedup vs baseline: 3.5539x; 1.0322x over previous
//
#include <hip/hip_runtime.h>
#include <math.h>

#define NN 1024
#define NNP 1025
#define DD 256
#define CC 5
#define G3 768
#define MAXT 512
#define NA 70

typedef _Float16 v8h __attribute__((ext_vector_type(8)));
typedef float v4f __attribute__((ext_vector_type(4)));

__device__ __forceinline__ int scale_of(int a){ return (a<15)?0:((a<55)?1:2); }
__device__ __forceinline__ int off_of(int s){ return (s==0)?0:((s==1)?15:55); }

__device__ __forceinline__ float sigf(float x){ return __fdividef(1.f, 1.f + __expf(-x)); }
__device__ __forceinline__ float tanhf_fast(float x){ return 1.f - __fdividef(2.f, __expf(2.f*x) + 1.f); }

// K0: tpos = time_positions * audio_len ; abn = softmax(node_pred)[:,0]
__global__ void prep_kernel(const float* __restrict__ tp_in, const float* __restrict__ node_pred,
                            const float* __restrict__ audio_len,
                            float* __restrict__ tpos, float* __restrict__ abn){
  int i = blockIdx.x*blockDim.x + threadIdx.x;
  if (i >= NN) return;
  tpos[i] = tp_in[i]*audio_len[0];
  float pv[CC]; float m = -1e30f;
  for (int c=0;c<CC;++c){ pv[c]=node_pred[i*CC+c]; m=fmaxf(m,pv[c]); }
  float s=0.f;
  for (int c=0;c<CC;++c) s += expf(pv[c]-m);
  abn[i] = expf(pv[0]-m)/s;
}

// K1: per-anchor stable gather of masked node indices + counts (ballot prefix)
__global__ void order_kernel(const float* __restrict__ tpos, const float* __restrict__ anchors,
                             int* __restrict__ order, int* __restrict__ cnteff){
  int a = blockIdx.x; int lane = threadIdx.x; // 64 threads = 1 wave
  float s = anchors[2*a], e = anchors[2*a+1];
  int* ord = order + a*MAXT;
  int cnt = 0;
  for (int base=0; base<NN; base+=64){
    float tp = tpos[base+lane];
    bool msk = (tp>=s)&&(tp<=e);
    unsigned long long bal = __ballot(msk);
    int off = (int)__popcll(bal & ((1ull<<lane)-1ull));
    if (msk && (cnt+off)<MAXT) ord[cnt+off] = base+lane;
    cnt += (int)__popcll(bal);
  }
  if (lane==0){ int c = cnt<MAXT?cnt:MAXT; cnteff[2*a]=c; cnteff[2*a+1]=(c>0)?c:1; }
}

// K2: pack whh into MFMA B-fragments grouped per-wave as 6 col-tiles:
// nt0,1 = r cols [w*32+0..15],[+16..31]; nt2,3 = z; nt4,5 = n.
// One thread emits one uint4 (4 fp16-pairs): i = ((((sd*8+w)*64+lane)*6+nt)*8+q)
__global__ void pack_whhB(const float* __restrict__ whh, uint4* __restrict__ dst){
  int i = blockIdx.x*256 + threadIdx.x;
  if (i >= 6*8*64*48) return;
  int q    = i & 7;
  int nt   = (i>>3) % 6;
  int lane = (i/48) & 63;
  int wv   = (i/3072) & 7;
  int sd   = i/24576;
  int gt = nt>>1, half = nt&1;
  int j = gt*256 + wv*32 + half*16 + (lane&15);
  int kbase = 32*q + 8*(lane>>4);
  const float* src = whh + ((size_t)sd*G3 + j)*DD + kbase;
  unsigned int u[4];
  #pragma unroll
  for (int rp=0;rp<4;++rp){
    _Float16 a = (_Float16)src[2*rp];
    _Float16 b = (_Float16)src[2*rp+1];
    unsigned short ua = __builtin_bit_cast(unsigned short, a);
    unsigned short ub = __builtin_bit_cast(unsigned short, b);
    u[rp] = (unsigned int)ua | ((unsigned int)ub<<16);
  }
  uint4 v; v.x=u[0]; v.y=u[1]; v.z=u[2]; v.w=u[3];
  dst[i] = v;
}

// K3: E_perm[sd][node][w][cl][slot] = emb.wih^T + bih (+bhh for r,z slots)
// slots: 0:r0 1:z0 2:n0 3:r16 4:z16 5:n16 6,7:pad ; per node 8w*16cl*8 = 1024 floats
__global__ __launch_bounds__(256) void e_gemm(const float* __restrict__ emb, const float* __restrict__ wih,
                       const float* __restrict__ bih, const float* __restrict__ bhh,
                       float* __restrict__ E){
  int sd = blockIdx.z;
  int row0 = blockIdx.x*64, col0 = blockIdx.y*64;
  const float* W = wih + (size_t)sd*G3*DD;
  __shared__ float As[64][65];
  __shared__ float Bs[64][65];
  int tid = threadIdx.x;
  int tr = tid>>4, tc = tid&15;
  float acc[4][4] = {};
  for (int kb=0; kb<4; ++kb){
    for (int i=0;i<4;++i){
      int e4 = i*256 + tid;
      int rr = e4>>4, qq = e4&15;
      float4 av = reinterpret_cast<const float4*>(emb)[ (size_t)(row0+rr)*64 + kb*16 + qq ];
      As[rr][qq*4+0]=av.x; As[rr][qq*4+1]=av.y; As[rr][qq*4+2]=av.z; As[rr][qq*4+3]=av.w;
      float4 bv = reinterpret_cast<const float4*>(W)[ (size_t)(col0+rr)*64 + kb*16 + qq ];
      Bs[rr][qq*4+0]=bv.x; Bs[rr][qq*4+1]=bv.y; Bs[rr][qq*4+2]=bv.z; Bs[rr][qq*4+3]=bv.w;
    }
    __syncthreads();
    for (int k=0;k<64;++k){
      float a0[4], b0[4];
      #pragma unroll
      for (int i=0;i<4;++i) a0[i]=As[tr*4+i][k];
      #pragma unroll
      for (int j=0;j<4;++j) b0[j]=Bs[tc*4+j][k];
      #pragma unroll
      for (int i=0;i<4;++i)
        #pragma unroll
        for (int j=0;j<4;++j)
          acc[i][j] += a0[i]*b0[j];
    }
    __syncthreads();
  }
  for (int i=0;i<4;++i){
    int row = row0 + tr*4 + i;
    for (int j=0;j<4;++j){
      int col = col0 + tc*4 + j;
      int gt = col>>8; int c = col&255;
      int wv = c>>5; int mm = c&31; int half = mm>>4; int cl = mm&15;
      int slot = half*3 + gt;
      float val = acc[i][j] + bih[sd*G3+col] + ((gt<2)? bhh[sd*G3+col] : 0.f);
      E[(((size_t)sd*NNP + row)*8 + wv)*128 + cl*8 + slot] = val;
    }
  }
}

// K3b: fake node row NN = pure bias (used for masked steps / cnt==0)
__global__ void fill_bias(const float* __restrict__ bih, const float* __restrict__ bhh,
                          float* __restrict__ E){
  int i = blockIdx.x*256 + threadIdx.x;   // 6*8*16*6 = 4608
  if (i >= 6*8*16*6) return;
  int slot = i % 6; int cl = (i/6)&15; int wv = (i/96)&7; int sd = i/768;
  int half = slot/3, gt = slot%3;
  int j = gt*256 + wv*32 + half*16 + cl;
  float v = bih[sd*G3+j] + ((gt<2)? bhh[sd*G3+j] : 0.f);
  E[(((size_t)sd*NNP + NN)*8 + wv)*128 + cl*8 + slot] = v;
}

// K4: per-matrix absmax -> quant scale (9 matrices)
__global__ void absmax_kernel(const float* __restrict__ w1, const float* __restrict__ w2,
                              const float* __restrict__ w30, const float* __restrict__ w31,
                              const float* __restrict__ w32, float* __restrict__ qs){
  int m = blockIdx.x, tid = threadIdx.x;
  const float* p; int n;
  if (m<3){ p = w1 + (size_t)m*256*519; n = 256*519; }
  else if (m<6){ p = w2 + (size_t)(m-3)*256*256; n = 256*256; }
  else { p = (m==6)?w30:((m==7)?w31:w32); n = ((m==7)?125:165)*256; }
  float mx = 0.f;
  for (int i=tid;i<n;i+=256) mx = fmaxf(mx, fabsf(p[i]));
  __shared__ float red[256];
  red[tid]=mx; __syncthreads();
  for (int sft=128; sft>0; sft>>=1){ if (tid<sft) red[tid]=fmaxf(red[tid],red[tid+sft]); __syncthreads(); }
  if (tid==0) qs[m] = fmaxf(red[0]/127.f, 1e-8f);
}

// K5: sequential GRU. One block per (anchor, direction); 8 waves x 96 gates.
// Lane-local nonlinearity: lane l owns h-columns w*32+(l&15) and +16.
// One barrier per step, double-buffered fp16 h in LDS.
__global__ __launch_bounds__(512, 2) void gru_kernel(
                           const float* __restrict__ E, const uint4* __restrict__ whhB,
                           const float* __restrict__ bhh,
                           const int* __restrict__ order, const int* __restrict__ cnteff,
                           float* __restrict__ hout){
  int a = blockIdx.x>>1, d = blockIdx.x&1;
  int si = scale_of(a);
  int sd = si*2+d;
  int tid = threadIdx.x;
  int w = tid>>6, lane = tid&63;
  int l15 = lane&15, g16 = lane>>4;

  __shared__ int ord_s[MAXT];
  __shared__ alignas(16) _Float16 h16[2][DD];

  ord_s[tid] = order[a*MAXT + tid];
  if (tid < DD) h16[0][tid] = (_Float16)0.f;

  int cnt = cnteff[2*a], eff = cnteff[2*a+1];

  int c0 = w*32 + l15, c1 = c0 + 16;
  float bn0 = bhh[sd*G3 + 2*DD + c0];
  float bn1 = bhh[sd*G3 + 2*DD + c1];

  // B fragments: 48 x uint4 = 192 dwords resident
  v8h bf[6][8];
  {
    const uint4* wp = whhB + (((size_t)sd*8 + w)*64 + lane)*48;
    #pragma unroll
    for (int nt=0;nt<6;++nt)
      #pragma unroll
      for (int q=0;q<8;++q)
        bf[nt][q] = __builtin_bit_cast(v8h, wp[nt*8+q]);
  }

  const float4* Eb = reinterpret_cast<const float4*>(E) + (size_t)sd*NNP*256;
  int lidx = (w*16 + l15)*2;

  __syncthreads();

  float h0 = 0.f, h1 = 0.f;
  float4 ga, gb;
  {
    int idx0 = d ? (eff-1) : 0;
    int n0 = (idx0 < cnt) ? ord_s[idx0] : NN;
    const float4* p = Eb + (size_t)n0*256 + lidx;
    ga = p[0]; gb = p[1];
  }

  for (int t=0;t<eff;++t){
    int p = t & 1;
    v4f acc0={0.f,0.f,0.f,0.f}, acc1={0.f,0.f,0.f,0.f};
    v4f acc2={0.f,0.f,0.f,0.f}, acc3={0.f,0.f,0.f,0.f};
    v4f acc4={bn0,bn0,bn0,bn0}, acc5={bn1,bn1,bn1,bn1};
    #pragma unroll
    for (int q=0;q<8;++q){
      v8h af = *reinterpret_cast<const v8h*>(&h16[p][32*q + 8*g16]);
      acc0 = __builtin_amdgcn_mfma_f32_16x16x32_f16(af, bf[0][q], acc0, 0,0,0);
      acc1 = __builtin_amdgcn_mfma_f32_16x16x32_f16(af, bf[1][q], acc1, 0,0,0);
      acc2 = __builtin_amdgcn_mfma_f32_16x16x32_f16(af, bf[2][q], acc2, 0,0,0);
      acc3 = __builtin_amdgcn_mfma_f32_16x16x32_f16(af, bf[3][q], acc3, 0,0,0);
      acc4 = __builtin_amdgcn_mfma_f32_16x16x32_f16(af, bf[4][q], acc4, 0,0,0);
      acc5 = __builtin_amdgcn_mfma_f32_16x16x32_f16(af, bf[5][q], acc5, 0,0,0);
    }
    float4 fa = ga, fb = gb;
    if (t+1 < eff){
      int idx1 = d ? (eff-2-t) : (t+1);
      int n1 = (idx1 < cnt) ? ord_s[idx1] : NN;
      const float4* pp = Eb + (size_t)n1*256 + lidx;
      ga = pp[0]; gb = pp[1];
    }
    // lane-local GRU cell for columns c0, c1
    float r0 = sigf(fa.x + acc0[0]);
    float z0 = sigf(fa.y + acc2[0]);
    float n0v = tanhf_fast(fa.z + r0*acc4[0]);
    h0 = z0*(h0 - n0v) + n0v;
    float r1 = sigf(fa.w + acc1[0]);
    float z1 = sigf(fb.x + acc3[0]);
    float n1v = tanhf_fast(fb.y + r1*acc5[0]);
    h1 = z1*(h1 - n1v) + n1v;
    if (g16 == 0)      h16[p^1][c0] = (_Float16)h0;
    else if (g16 == 1) h16[p^1][c1] = (_Float16)h1;
    __syncthreads();
  }
  if (g16 == 0)      hout[(size_t)(2*a+d)*DD + c0] = h0;
  else if (g16 == 1) hout[(size_t)(2*a+d)*DD + c1] = h1;
}

// K6: per-anchor MLP (int8 fake-quant on the fly) + softmax-weighted refinement head
__global__ __launch_bounds__(256) void mlp_kernel(const float* __restrict__ hout, const float* __restrict__ abn,
                           const float* __restrict__ anchors, const float* __restrict__ audio_len,
                           const float* __restrict__ w1, const float* __restrict__ w2,
                           const float* __restrict__ w30, const float* __restrict__ w31, const float* __restrict__ w32,
                           const float* __restrict__ sw0, const float* __restrict__ ew0,
                           const float* __restrict__ sw1, const float* __restrict__ ew1,
                           const float* __restrict__ sw2, const float* __restrict__ ew2,
                           const float* __restrict__ qs, float* __restrict__ out){
  int a = blockIdx.x, tid = threadIdx.x;
  int si = scale_of(a);
  int il = a - off_of(si);
  float s = anchors[2*a], e = anchors[2*a+1];
  float al = audio_len[0];
  __shared__ float feat[520];
  __shared__ float h1[256], h2[256], o[168];
  feat[tid]    = hout[(size_t)(2*a+0)*DD + tid];
  feat[DD+tid] = hout[(size_t)(2*a+1)*DD + tid];
  if (tid==0){
    feat[512]=abn[il];
    feat[513]=(s+e)*0.5f/al;
    feat[514]=(e-s)/al;
    feat[515]=0.f; feat[516]=0.f; feat[517]=0.f; feat[518]=0.f; feat[519]=0.f;
  }
  __syncthreads();
  {
    float sc = qs[si], inv = 1.f/sc;
    const float* row = w1 + ((size_t)si*256 + tid)*519;
    float acc=0.f;
    for (int k=0;k<519;++k){
      float q = rintf(row[k]*inv);
      q = fminf(fmaxf(q,-128.f),127.f);
      acc += feat[k]*(q*sc);
    }
    h1[tid]=fmaxf(acc,0.f);
  }
  __syncthreads();
  {
    float sc = qs[3+si], inv = 1.f/sc;
    const float* row = w2 + ((size_t)si*256 + tid)*256;
    float acc=0.f;
    for (int k=0;k<256;++k){
      float q = rintf(row[k]*inv);
      q = fminf(fmaxf(q,-128.f),127.f);
      acc += h1[k]*(q*sc);
    }
    h2[tid]=fmaxf(acc,0.f);
  }
  __syncthreads();
  int nout = (si==1)?125:165;
  const float* w3 = (si==0)?w30:((si==1)?w31:w32);
  if (tid<nout){
    float sc = qs[6+si], inv = 1.f/sc;
    const float* row = w3 + (size_t)tid*256;
    float acc=0.f;
    for (int k=0;k<256;++k){
      float q = rintf(row[k]*inv);
      q = fminf(fmaxf(q,-128.f),127.f);
      acc += h2[k]*(q*sc);
    }
    o[tid]=acc;
  }
  __syncthreads();
  if (tid==0){
    int b = (si==1)?60:80;
    const float* sw = (si==0)?sw0:((si==1)?sw1:sw2);
    const float* ew = (si==0)?ew0:((si==1)?ew1:ew2);
    float m=-1e30f; for (int i=0;i<b;++i) m=fmaxf(m,o[i]);
    float se=0.f, wsum=0.f;
    for (int i=0;i<b;++i){ float t=expf(o[i]-m); se+=t; wsum+=t*sw[i]; }
    float so = wsum/se;
    m=-1e30f; for (int i=0;i<b;++i) m=fmaxf(m,o[b+i]);
    se=0.f; wsum=0.f;
    for (int i=0;i<b;++i){ float t=expf(o[b+i]-m); se+=t; wsum+=t*ew[i]; }
    float eo = wsum/se;
    out[2*a]   = fminf(fmaxf(s+so,0.f),al);
    out[2*a+1] = fminf(fmaxf(e+eo,0.f),al);
    out[140+a] = o[2*b];
    for (int c2=0;c2<4;++c2) out[210+4*a+c2] = o[2*b+1+c2];
  }
}

extern "C" void kernel_launch(void* const* d_in, const int* in_sizes, int n_in,
                              void* d_out, int out_size, void* d_ws, size_t ws_size,
                              hipStream_t stream){
  const float* emb   = (const float*)d_in[0];
  const float* tpin  = (const float*)d_in[1];
  const float* npred = (const float*)d_in[2];
  const float* alen  = (const float*)d_in[3];
  const float* anch  = (const float*)d_in[4];
  const float* wih   = (const float*)d_in[5];
  const float* whh   = (const float*)d_in[6];
  const float* bih   = (const float*)d_in[7];
  const float* bhh   = (const float*)d_in[8];
  const float* w1    = (const float*)d_in[9];
  const float* w2    = (const float*)d_in[10];
  const float* w30   = (const float*)d_in[11];
  const float* w31   = (const float*)d_in[12];
  const float* w32   = (const float*)d_in[13];
  const float* sw0   = (const float*)d_in[14];
  const float* ew0   = (const float*)d_in[15];
  const float* sw1   = (const float*)d_in[16];
  const float* ew1   = (const float*)d_in[17];
  const float* sw2   = (const float*)d_in[18];
  const float* ew2   = (const float*)d_in[19];

  char* ws = (char*)d_ws;
  size_t off = 0;
  auto take = [&](size_t bytes)->char*{
    char* p = ws + off;
    off = (off + bytes + 255) & ~(size_t)255;
    return p;
  };
  float* tpos   = (float*)take((size_t)NN*4);
  float* abn    = (float*)take((size_t)NN*4);
  int*   order_ = (int*)  take((size_t)NA*MAXT*4);
  int*   cnteff = (int*)  take((size_t)NA*2*4);
  float* qs     = (float*)take(16*4);
  uint4* whhB   = (uint4*)take((size_t)6*8*64*48*16);
  float* E      = (float*)take((size_t)6*NNP*1024*4);
  float* hout   = (float*)take((size_t)NA*2*DD*4);
  (void)ws_size; (void)in_sizes; (void)n_in; (void)out_size;

  prep_kernel<<<dim3((NN+255)/256), dim3(256), 0, stream>>>(tpin, npred, alen, tpos, abn);
  order_kernel<<<dim3(NA), dim3(64), 0, stream>>>(tpos, anch, order_, cnteff);
  pack_whhB<<<dim3((6*8*64*48+255)/256), dim3(256), 0, stream>>>(whh, whhB);
  e_gemm<<<dim3(16,12,6), dim3(256), 0, stream>>>(emb, wih, bih, bhh, E);
  fill_bias<<<dim3((6*8*16*6+255)/256), dim3(256), 0, stream>>>(bih, bhh, E);
  absmax_kernel<<<dim3(9), dim3(256), 0, stream>>>(w1, w2, w30, w31, w32, qs);
  gru_kernel<<<dim3(NA*2), dim3(512), 0, stream>>>(E, whhB, bhh, order_, cnteff, hout);
  mlp_kernel<<<dim3(NA), dim3(256), 0, stream>>>(hout, abn, anch, alen, w1, w2, w30, w31, w32,
                                                 sw0, ew0, sw1, ew1, sw2, ew2, qs, (float*)d_out);
}